// Round 8
// baseline (485.581 us; speedup 1.0000x reference)
//
#include <hip/hip_runtime.h>

#define BB 16
#define NN 4096
#define CC 128
#define PP 1024
#define SS 32
#define MM (BB*PP*SS)       // 524288
#define NBLK 8192           // stat-partial stride
#define OFF_NF 49152        // 16*1024*3
#define OFF_SI 4243456      // 49152 + 16*256*1024

typedef unsigned short u16;
typedef unsigned int u32;
typedef __attribute__((ext_vector_type(8))) short short8v;
typedef __attribute__((ext_vector_type(4))) float f32x4;

__device__ __forceinline__ float b2f(u16 u) {
    union { float f; unsigned i; } x; x.i = ((unsigned)u) << 16; return x.f;
}
__device__ __forceinline__ u16 f2b(float f) {   // RTNE bf16
    union { float f; unsigned i; } x; x.f = f;
    unsigned r = x.i + 0x7fffu + ((x.i >> 16) & 1u);
    return (u16)(r >> 16);
}
__device__ __forceinline__ float2 act2(u32 u, float2 s0, float2 s1) {
    union { float f; unsigned i; } a, b;
    a.i = u << 16; b.i = u & 0xffff0000u;
    return make_float2(fmaxf(fmaf(s0.x, a.f, s0.y), 0.f),
                       fmaxf(fmaf(s1.x, b.f, s1.y), 0.f));
}
__device__ __forceinline__ u32 packbf(float flo, float fhi) {
    union { float f; unsigned i; } x0, x1; x0.f = flo; x1.f = fhi;
    return __builtin_amdgcn_perm(x1.i, x0.i, 0x07060302u);
}
__device__ __forceinline__ u32 packbf_rtne(float flo, float fhi) {
    union { float f; unsigned i; } x0, x1; x0.f = flo; x1.f = fhi;
    u32 r0 = x0.i + 0x7fffu + ((x0.i >> 16) & 1u);
    u32 r1 = x1.i + 0x7fffu + ((x1.i >> 16) & 1u);
    return __builtin_amdgcn_perm(r1, r0, 0x07060302u);
}
__device__ __forceinline__ u32 act_pack(u32 u, float2 s0, float2 s1) {
    float2 f = act2(u, s0, s1);
    return packbf(f.x, f.y);
}
__device__ __forceinline__ short8v as_s8(uint4 v) {
    union { uint4 u; short8v s; } x; x.u = v; return x.s;
}

#define MFMA16(a,b,c) __builtin_amdgcn_mfma_f32_16x16x32_bf16(a,b,c,0,0,0)

// ---------------------------------------------------------------------------
// k_init: new_xyz + sample_idxs + w0t (xyz rows, fp32) + w0b/w1b/w2b (bf16)
// ---------------------------------------------------------------------------
__global__ void k_init(const float* __restrict__ xyz, const float* __restrict__ w0,
                       const float* __restrict__ w1, const float* __restrict__ w2,
                       float* __restrict__ out, float* __restrict__ w0t,
                       u16* __restrict__ w0b, u16* __restrict__ w1b,
                       u16* __restrict__ w2b) {
    int i = blockIdx.x * 256 + threadIdx.x;
    if (i < 49152) {
        int b = i / 3072, r = i % 3072;
        out[i] = xyz[b * 12288 + r];
        return;
    }
    int j = i - 49152;
    if (j < 16384) { out[OFF_SI + j] = (float)(j & 1023); return; }
    int e = j - 16384;
    if (e < 384) { w0t[e] = w0[(e & 127) * 131 + (e >> 7)]; return; }
    int f = e - 384;
    if (f < 16384) { w0b[f] = f2b(w0[(f >> 7) * 131 + 3 + (f & 127)]); return; }
    int h = f - 16384;
    if (h < 16384) { w1b[h] = f2b(w1[h]); return; }
    int k2 = h - 16384;
    if (k2 < 32768) { w2b[k2] = f2b(w2[k2]); }
}

// ---------------------------------------------------------------------------
// k_ballquery: wave-per-center ballot scan.
// ---------------------------------------------------------------------------
__global__ __launch_bounds__(256) void k_ballquery(const float* __restrict__ xyz,
                                                   int* __restrict__ oidx,
                                                   float* __restrict__ relx,
                                                   float* __restrict__ rely,
                                                   float* __restrict__ relz) {
    __shared__ float sx[NN], sy[NN], sz[NN];
    int t = threadIdx.x, w = t >> 6, lane = t & 63;
    int b = blockIdx.x >> 8;
    int p = (blockIdx.x & 255) * 4 + w;
    const float* xb = xyz + (long)b * NN * 3;
    for (int i = t; i < NN; i += 256) {
        sx[i] = xb[3 * i]; sy[i] = xb[3 * i + 1]; sz[i] = xb[3 * i + 2];
    }
    __syncthreads();
    const float R2 = (float)(0.4 * 0.4);
    float cx = sx[p], cy = sy[p], cz = sz[p];
    int o = (b * PP + p) * SS;
    int cnt = 0, firstn = 0;
    float fdx = 0.f, fdy = 0.f, fdz = 0.f;
    for (int c = 0; c < 64 && cnt < 32; ++c) {
        int n = c * 64 + lane;
        float dx = __fsub_rn(sx[n], cx);
        float dy = __fsub_rn(sy[n], cy);
        float dz = __fsub_rn(sz[n], cz);
        float d2 = __fadd_rn(__fadd_rn(__fmul_rn(dx, dx), __fmul_rn(dy, dy)),
                             __fmul_rn(dz, dz));
        bool hit = d2 < R2;
        unsigned long long mask = __ballot(hit);
        if (mask) {
            if (cnt == 0) {
                int fl = __ffsll(mask) - 1;
                firstn = c * 64 + fl;
                fdx = __shfl(dx, fl); fdy = __shfl(dy, fl); fdz = __shfl(dz, fl);
            }
            int pos = cnt + __popcll(mask & ((1ull << lane) - 1ull));
            if (hit && pos < 32) {
                oidx[o + pos] = n;
                relx[o + pos] = dx; rely[o + pos] = dy; relz[o + pos] = dz;
            }
            cnt += __popcll(mask);
        }
    }
    if (lane < 32 && lane >= cnt) {
        oidx[o + lane] = firstn;
        relx[o + lane] = fdx; rely[o + lane] = fdy; relz[o + lane] = fdz;
    }
}

// ---------------------------------------------------------------------------
// k_f1: F1[n][co] = sum_ci feat[ci][n] * w0[co][3+ci] via MFMA (fp32 out).
// ---------------------------------------------------------------------------
__global__ __launch_bounds__(256) void k_f1(const float* __restrict__ feat,
                                            const u16* __restrict__ w0b,
                                            float* __restrict__ F1) {
    __shared__ uint4 abuf[64 * 17];
    int t = threadIdx.x;
    int w = t >> 6, lane = t & 63, q = lane >> 4, l16 = lane & 15;
    int cb = (w & 1) * 64, wm0 = (w >> 1) * 32;
    short8v bf[4][4];
#pragma unroll
    for (int ct = 0; ct < 4; ++ct)
#pragma unroll
        for (int k0 = 0; k0 < 4; ++k0)
            bf[ct][k0] = *(const short8v*)(w0b + (cb + ct * 16 + l16) * 128 + k0 * 32 + q * 8);
    int nl = t & 63, cg = t >> 6;
    const float* fcol = feat + (long)(blockIdx.x >> 6) * (128 * 4096)
                             + (long)(blockIdx.x & 63) * 64 + nl;
#pragma unroll
    for (int pp = 0; pp < 4; ++pp) {
        int oct = cg + 4 * pp;
        float v[8];
#pragma unroll
        for (int r = 0; r < 8; ++r) v[r] = fcol[(long)(oct * 8 + r) * 4096];
        uint4 ov;
        ov.x = packbf_rtne(v[0], v[1]); ov.y = packbf_rtne(v[2], v[3]);
        ov.z = packbf_rtne(v[4], v[5]); ov.w = packbf_rtne(v[6], v[7]);
        abuf[nl * 17 + ((oct + nl) & 15)] = ov;
    }
    __syncthreads();
    f32x4 acc[2][4];
#pragma unroll
    for (int mt = 0; mt < 2; ++mt)
#pragma unroll
        for (int ct = 0; ct < 4; ++ct) acc[mt][ct] = (f32x4){0.f, 0.f, 0.f, 0.f};
#pragma unroll
    for (int mt = 0; mt < 2; ++mt) {
        int row = wm0 + mt * 16 + l16;
#pragma unroll
        for (int k0 = 0; k0 < 4; ++k0) {
            uint4 vv = abuf[row * 17 + ((k0 * 4 + q + row) & 15)];
            short8v af = as_s8(vv);
#pragma unroll
            for (int ct = 0; ct < 4; ++ct)
                acc[mt][ct] = MFMA16(af, bf[ct][k0], acc[mt][ct]);
        }
    }
    long nbase = (long)blockIdx.x * 64;
#pragma unroll
    for (int mt = 0; mt < 2; ++mt)
#pragma unroll
        for (int ct = 0; ct < 4; ++ct)
#pragma unroll
            for (int r = 0; r < 4; ++r)
                F1[(nbase + wm0 + mt * 16 + q * 4 + r) * 128 + cb + ct * 16 + l16]
                    = acc[mt][ct][r];
}

// ---------------------------------------------------------------------------
// k_y0: wave reads one 512B F1 row per m (float2/lane), packed u32 stores.
// ---------------------------------------------------------------------------
__global__ __launch_bounds__(256) void k_y0(const float* __restrict__ relx,
                                            const float* __restrict__ rely,
                                            const float* __restrict__ relz,
                                            const float* __restrict__ w0t,
                                            const float* __restrict__ F1,
                                            const int* __restrict__ idx,
                                            u16* __restrict__ y0,
                                            float* __restrict__ part,
                                            float* __restrict__ partq) {
    int t = threadIdx.x, w = t >> 6, lane = t & 63;
    long m0 = (long)blockIdx.x * 64;
    int c0 = 2 * lane;
    float wx0 = w0t[c0],       wx1 = w0t[c0 + 1];
    float wy0 = w0t[128 + c0], wy1 = w0t[128 + c0 + 1];
    float wz0 = w0t[256 + c0], wz1 = w0t[256 + c0 + 1];
    float s1a = 0.f, s1b = 0.f, s2a = 0.f, s2b = 0.f;
    u32* yo = (u32*)y0;
#pragma unroll 4
    for (int i = 0; i < 16; ++i) {
        long m = m0 + w + 4 * i;
        int b = (int)(m >> 15);
        int id = idx[m];
        float rx = relx[m], ry = rely[m], rz = relz[m];
        float2 f = *(const float2*)(F1 + ((long)(b * NN + id)) * 128 + c0);
        float v0 = fmaf(wx0, rx, fmaf(wy0, ry, fmaf(wz0, rz, f.x)));
        float v1 = fmaf(wx1, rx, fmaf(wy1, ry, fmaf(wz1, rz, f.y)));
        yo[m * 64 + lane] = packbf_rtne(v0, v1);
        s1a += v0; s2a = fmaf(v0, v0, s2a);
        s1b += v1; s2b = fmaf(v1, v1, s2b);
    }
    __shared__ float r1[128][4], r2[128][4];
    r1[c0][w] = s1a; r1[c0 + 1][w] = s1b;
    r2[c0][w] = s2a; r2[c0 + 1][w] = s2b;
    __syncthreads();
    if (t < 128) {
        float a1 = r1[t][0] + r1[t][1] + r1[t][2] + r1[t][3];
        float a2 = r2[t][0] + r2[t][1] + r2[t][2] + r2[t][3];
        part [(long)t * NBLK + blockIdx.x] = a1;
        partq[(long)t * NBLK + blockIdx.x] = a2;
    }
}

// ---------------------------------------------------------------------------
// k_bnfin: reduce per-channel partials -> (scale, shift). grid = #channels.
// ---------------------------------------------------------------------------
__global__ void k_bnfin(const float* __restrict__ part, const float* __restrict__ partq,
                        const float* __restrict__ g, const float* __restrict__ beta,
                        float* __restrict__ st, int nblk) {
    int co = blockIdx.x, t = threadIdx.x;
    const float* p1 = part + (long)co * NBLK;
    const float* p2 = partq + (long)co * NBLK;
    float s1 = 0.f, s2 = 0.f;
    for (int j = t; j < nblk; j += 256) { s1 += p1[j]; s2 += p2[j]; }
    __shared__ float r1[256], r2[256];
    r1[t] = s1; r2[t] = s2; __syncthreads();
    for (int off = 128; off > 0; off >>= 1) {
        if (t < off) { r1[t] += r1[t + off]; r2[t] += r2[t + off]; }
        __syncthreads();
    }
    if (t == 0) {
        const float inv = 1.f / (float)MM;
        float mean = r1[0] * inv;
        float var = r2[0] * inv - mean * mean;
        float sc = g[co] * rsqrtf(var + 1e-5f);
        st[2 * co] = sc;
        st[2 * co + 1] = fmaf(-mean, sc, beta[co]);
    }
}

// ---------------------------------------------------------------------------
// k_conv1: y1 = W1 . act0(y0) IN-PLACE. Block = 512m x 128co, 8 chunks of 64m.
// Rotation swizzle; launch_bounds(256,3) for 12 waves/CU.
// ---------------------------------------------------------------------------
__global__ __launch_bounds__(256, 3) void k_conv1(u16* __restrict__ y,
                                                  const u16* __restrict__ w1b,
                                                  const float* __restrict__ st0,
                                                  float* __restrict__ part,
                                                  float* __restrict__ partq) {
    __shared__ uint4 abuf[2][64 * 17];
    __shared__ float2 sst[128];
    __shared__ float sredA[4][64], sredB[4][64];
    int t = threadIdx.x;
    if (t < 128) sst[t] = ((const float2*)st0)[t];
    int w = t >> 6, lane = t & 63, q = lane >> 4, l16 = lane & 15;
    int wm0 = (w >> 1) * 32, cb = (w & 1) * 64;
    short8v bf[4][4];
#pragma unroll
    for (int ct = 0; ct < 4; ++ct)
#pragma unroll
        for (int k0 = 0; k0 < 4; ++k0)
            bf[ct][k0] = *(const short8v*)(w1b + (cb + ct * 16 + l16) * 128 + k0 * 32 + q * 8);
    __syncthreads();
    long m0b = (long)blockIdx.x * 512;
    float s1[4] = {0.f, 0.f, 0.f, 0.f}, s2[4] = {0.f, 0.f, 0.f, 0.f};
    int sr = t >> 4, sc16 = t & 15;
    for (int c = 0; c < 8; ++c) {
        long m0 = m0b + c * 64;
        uint4* ab = abuf[c & 1];
        const uint4* gsrc = (const uint4*)y;
#pragma unroll
        for (int p = 0; p < 4; ++p) {
            int r = p * 16 + sr;
            uint4 d = gsrc[(m0 + r) * 16 + sc16];
            uint4 o;
            o.x = act_pack(d.x, sst[sc16 * 8 + 0], sst[sc16 * 8 + 1]);
            o.y = act_pack(d.y, sst[sc16 * 8 + 2], sst[sc16 * 8 + 3]);
            o.z = act_pack(d.z, sst[sc16 * 8 + 4], sst[sc16 * 8 + 5]);
            o.w = act_pack(d.w, sst[sc16 * 8 + 6], sst[sc16 * 8 + 7]);
            ab[r * 17 + ((sc16 + r) & 15)] = o;
        }
        __syncthreads();
        f32x4 acc[2][4];
#pragma unroll
        for (int mt = 0; mt < 2; ++mt)
#pragma unroll
            for (int ct = 0; ct < 4; ++ct) acc[mt][ct] = (f32x4){0.f, 0.f, 0.f, 0.f};
#pragma unroll
        for (int mt = 0; mt < 2; ++mt) {
            int row = wm0 + mt * 16 + l16;
#pragma unroll
            for (int k0 = 0; k0 < 4; ++k0) {
                uint4 v = ab[row * 17 + ((k0 * 4 + q + row) & 15)];
                short8v af = as_s8(v);
#pragma unroll
                for (int ct = 0; ct < 4; ++ct)
                    acc[mt][ct] = MFMA16(af, bf[ct][k0], acc[mt][ct]);
            }
        }
#pragma unroll
        for (int mt = 0; mt < 2; ++mt)
#pragma unroll
            for (int ct = 0; ct < 4; ++ct)
#pragma unroll
                for (int r = 0; r < 4; ++r) {
                    float v = acc[mt][ct][r];
                    y[(m0 + wm0 + mt * 16 + q * 4 + r) * 128 + cb + ct * 16 + l16] = f2b(v);
                    s1[ct] += v; s2[ct] = fmaf(v, v, s2[ct]);
                }
    }
#pragma unroll
    for (int ct = 0; ct < 4; ++ct) {
        float a = s1[ct], b = s2[ct];
        a += __shfl_xor(a, 16); a += __shfl_xor(a, 32);
        b += __shfl_xor(b, 16); b += __shfl_xor(b, 32);
        if (lane < 16) { sredA[w][ct * 16 + l16] = a; sredB[w][ct * 16 + l16] = b; }
    }
    __syncthreads();
    if (t < 128) {
        int h = t >> 6, cl = t & 63;
        part [(long)t * NBLK + blockIdx.x] = sredA[h][cl] + sredA[h + 2][cl];
        partq[(long)t * NBLK + blockIdx.x] = sredB[h][cl] + sredB[h + 2][cl];
    }
}

// ---------------------------------------------------------------------------
// k_conv2pool: y2 = W2 . act1(y1), raw min/max per 32-sample group, and
// layer-2 BN stat partials. Wave = 32m (mt=2) x 128co (ct=8).
// B-fragments loaded from global INSIDE the k-loop (L1/L2-hot, 512B/wave/chunk)
// instead of 128 resident VGPRs -- kills the round-7 spill. A-fragments
// preloaded per chunk (32 VGPRs). k0-outer order: 15 independent MFMAs
// between dependent ones. launch_bounds(256,3): 12 waves/CU.
// ---------------------------------------------------------------------------
__global__ __launch_bounds__(256, 3) void k_conv2pool(const u16* __restrict__ y1,
                                                      const u16* __restrict__ w2b,
                                                      const float* __restrict__ st1,
                                                      float* __restrict__ rawmax,
                                                      float* __restrict__ rawmin,
                                                      float* __restrict__ part,
                                                      float* __restrict__ partq) {
    __shared__ uint4 abuf[2][64 * 17];
    __shared__ float2 sst[128];
    __shared__ float sredA[4][128], sredB[4][128];
    int t = threadIdx.x;
    if (t < 128) sst[t] = ((const float2*)st1)[t];
    __syncthreads();
    int w = t >> 6, lane = t & 63, q = lane >> 4, l16 = lane & 15;
    int rh = w >> 1, chh = w & 1;
    const u16* wbase = w2b + (chh * 128 + l16) * 128 + q * 8;
    long m0b = (long)blockIdx.x * 512;
    int sr = t >> 4, sc16 = t & 15;
    float s1[8] = {0.f,0.f,0.f,0.f,0.f,0.f,0.f,0.f};
    float s2[8] = {0.f,0.f,0.f,0.f,0.f,0.f,0.f,0.f};
    for (int c = 0; c < 8; ++c) {
        long m0 = m0b + c * 64;
        uint4* ab = abuf[c & 1];
        const uint4* gsrc = (const uint4*)y1;
#pragma unroll
        for (int p = 0; p < 4; ++p) {
            int r = p * 16 + sr;
            uint4 d = gsrc[(m0 + r) * 16 + sc16];
            uint4 o;
            o.x = act_pack(d.x, sst[sc16 * 8 + 0], sst[sc16 * 8 + 1]);
            o.y = act_pack(d.y, sst[sc16 * 8 + 2], sst[sc16 * 8 + 3]);
            o.z = act_pack(d.z, sst[sc16 * 8 + 4], sst[sc16 * 8 + 5]);
            o.w = act_pack(d.w, sst[sc16 * 8 + 6], sst[sc16 * 8 + 7]);
            ab[r * 17 + ((sc16 + r) & 15)] = o;
        }
        __syncthreads();
        // A fragments for this wave's 32 rows (preload, 32 VGPRs)
        short8v af[2][4];
#pragma unroll
        for (int mt = 0; mt < 2; ++mt) {
            int row = rh * 32 + mt * 16 + l16;
#pragma unroll
            for (int k0 = 0; k0 < 4; ++k0)
                af[mt][k0] = as_s8(ab[row * 17 + ((k0 * 4 + q + row) & 15)]);
        }
        f32x4 acc[2][8];
#pragma unroll
        for (int mt = 0; mt < 2; ++mt)
#pragma unroll
            for (int ct = 0; ct < 8; ++ct) acc[mt][ct] = (f32x4){0.f, 0.f, 0.f, 0.f};
#pragma unroll
        for (int k0 = 0; k0 < 4; ++k0)
#pragma unroll
            for (int ct = 0; ct < 8; ++ct) {
                short8v bfv = *(const short8v*)(wbase + ct * (16 * 128) + k0 * 32);
                acc[0][ct] = MFMA16(af[0][k0], bfv, acc[0][ct]);
                acc[1][ct] = MFMA16(af[1][k0], bfv, acc[1][ct]);
            }
        // pooling (wave's 32 rows = one group) + stats
#pragma unroll
        for (int ct = 0; ct < 8; ++ct) {
            f32x4 a0 = acc[0][ct], a1 = acc[1][ct];
            s1[ct] += a0[0] + a0[1] + a0[2] + a0[3] + a1[0] + a1[1] + a1[2] + a1[3];
            s2[ct] = fmaf(a0[0], a0[0], s2[ct]); s2[ct] = fmaf(a0[1], a0[1], s2[ct]);
            s2[ct] = fmaf(a0[2], a0[2], s2[ct]); s2[ct] = fmaf(a0[3], a0[3], s2[ct]);
            s2[ct] = fmaf(a1[0], a1[0], s2[ct]); s2[ct] = fmaf(a1[1], a1[1], s2[ct]);
            s2[ct] = fmaf(a1[2], a1[2], s2[ct]); s2[ct] = fmaf(a1[3], a1[3], s2[ct]);
            float mx = fmaxf(fmaxf(fmaxf(a0[0], a0[1]), fmaxf(a0[2], a0[3])),
                             fmaxf(fmaxf(a1[0], a1[1]), fmaxf(a1[2], a1[3])));
            float mn = fminf(fminf(fminf(a0[0], a0[1]), fminf(a0[2], a0[3])),
                             fminf(fminf(a1[0], a1[1]), fminf(a1[2], a1[3])));
            mx = fmaxf(mx, __shfl_xor(mx, 16)); mx = fmaxf(mx, __shfl_xor(mx, 32));
            mn = fminf(mn, __shfl_xor(mn, 16)); mn = fminf(mn, __shfl_xor(mn, 32));
            if (lane < 16) {
                long bp = (long)blockIdx.x * 16 + c * 2 + rh;
                rawmax[bp * 256 + chh * 128 + ct * 16 + l16] = mx;
                rawmin[bp * 256 + chh * 128 + ct * 16 + l16] = mn;
            }
        }
    }
    // stat reduction: sum over q (shfl) then over row-half waves (LDS)
#pragma unroll
    for (int ct = 0; ct < 8; ++ct) {
        float a = s1[ct], b = s2[ct];
        a += __shfl_xor(a, 16); a += __shfl_xor(a, 32);
        b += __shfl_xor(b, 16); b += __shfl_xor(b, 32);
        if (lane < 16) { sredA[w][ct * 16 + l16] = a; sredB[w][ct * 16 + l16] = b; }
    }
    __syncthreads();
    {
        int h = t >> 7, cl = t & 127;      // co = h*128 + cl
        part [(long)t * NBLK + blockIdx.x] = sredA[h][cl] + sredA[h + 2][cl];
        partq[(long)t * NBLK + blockIdx.x] = sredB[h][cl] + sredB[h + 2][cl];
    }
}

// ---------------------------------------------------------------------------
// k_final: z = relu(sc>0 ? sc*max+sh : sc*min+sh); transpose to out[b][co][p].
// ---------------------------------------------------------------------------
__global__ void k_final(const float* __restrict__ rawmax, const float* __restrict__ rawmin,
                        const float* __restrict__ st2, float* __restrict__ out) {
    __shared__ float tile[32][33];
    int b = blockIdx.x >> 8;
    int p0 = ((blockIdx.x >> 3) & 31) * 32;
    int c0 = (blockIdx.x & 7) * 32;
    int j = threadIdx.x & 31, i0 = threadIdx.x >> 5;
    float sc = st2[2 * (c0 + j)], sh = st2[2 * (c0 + j) + 1];
#pragma unroll
    for (int rr = 0; rr < 4; ++rr) {
        int i = i0 + rr * 8;
        long idx = ((long)(b * 1024 + p0 + i)) * 256 + c0 + j;
        float v = sc > 0.f ? fmaf(sc, rawmax[idx], sh) : fmaf(sc, rawmin[idx], sh);
        tile[i][j] = fmaxf(v, 0.f);
    }
    __syncthreads();
#pragma unroll
    for (int rr = 0; rr < 4; ++rr) {
        int i = i0 + rr * 8;
        out[OFF_NF + (long)b * 262144 + (c0 + i) * 1024 + p0 + j] = tile[j][i];
    }
}

// ---------------------------------------------------------------------------
extern "C" void kernel_launch(void* const* d_in, const int* in_sizes, int n_in,
                              void* d_out, int out_size, void* d_ws, size_t ws_size,
                              hipStream_t stream) {
    (void)in_sizes; (void)n_in; (void)out_size; (void)ws_size;
    const float* xyz  = (const float*)d_in[0];
    const float* feat = (const float*)d_in[1];
    const float* w0   = (const float*)d_in[3];
    const float* g0   = (const float*)d_in[5];
    const float* be0  = (const float*)d_in[6];
    const float* w1   = (const float*)d_in[7];
    const float* g1   = (const float*)d_in[9];
    const float* be1  = (const float*)d_in[10];
    const float* w2   = (const float*)d_in[11];
    const float* g2   = (const float*)d_in[13];
    const float* be2  = (const float*)d_in[14];
    float* out = (float*)d_out;

    char* ws = (char*)d_ws;
    size_t off = 0;
    auto alloc = [&](size_t bytes) -> void* {
        void* p = ws + off;
        off = (off + bytes + 4095) & ~(size_t)4095;
        return p;
    };
    int*   idx    = (int*)  alloc((size_t)MM * 4);            // 2 MB
    float* relx   = (float*)alloc((size_t)MM * 4);            // 2 MB
    float* rely   = (float*)alloc((size_t)MM * 4);            // 2 MB
    float* relz   = (float*)alloc((size_t)MM * 4);            // 2 MB
    float* w0t    = (float*)alloc(3 * 128 * 4);
    u16*   w0b    = (u16*)  alloc(128 * 128 * 2);
    u16*   w1b    = (u16*)  alloc(128 * 128 * 2);
    u16*   w2b    = (u16*)  alloc(256 * 128 * 2);
    float* st0    = (float*)alloc(128 * 2 * 4);
    float* st1    = (float*)alloc(128 * 2 * 4);
    float* st2    = (float*)alloc(256 * 2 * 4);
    float* part   = (float*)alloc((size_t)256 * NBLK * 4);    // 8 MB
    float* partq  = (float*)alloc((size_t)256 * NBLK * 4);    // 8 MB
    float* F1     = (float*)alloc((size_t)BB * NN * 128 * 4); // 33.5 MB
    float* rawmax = (float*)alloc((size_t)BB * PP * 256 * 4); // 16 MB
    float* rawmin = (float*)alloc((size_t)BB * PP * 256 * 4); // 16 MB
    u16*   bufA   = (u16*)  alloc((size_t)MM * 128 * 2);      // 134 MB (y0 -> y1 in place)
    // total ~225 MB

    k_init<<<514, 256, 0, stream>>>(xyz, w0, w1, w2, out, w0t, w0b, w1b, w2b);
    k_ballquery<<<4096, 256, 0, stream>>>(xyz, idx, relx, rely, relz);
    k_f1<<<1024, 256, 0, stream>>>(feat, w0b, F1);
    k_y0<<<NBLK, 256, 0, stream>>>(relx, rely, relz, w0t, F1, idx, bufA, part, partq);
    k_bnfin<<<128, 256, 0, stream>>>(part, partq, g0, be0, st0, NBLK);
    k_conv1<<<1024, 256, 0, stream>>>(bufA, w1b, st0, part, partq);
    k_bnfin<<<128, 256, 0, stream>>>(part, partq, g1, be1, st1, 1024);
    k_conv2pool<<<1024, 256, 0, stream>>>(bufA, w2b, st1, rawmax, rawmin, part, partq);
    k_bnfin<<<256, 256, 0, stream>>>(part, partq, g2, be2, st2, 1024);
    k_final<<<4096, 256, 0, stream>>>(rawmax, rawmin, st2, out);
}

// Round 9
// 329.948 us; speedup vs baseline: 1.4717x; 1.4717x over previous
//
#include <hip/hip_runtime.h>

#define BB 16
#define NN 4096
#define CC 128
#define PP 1024
#define SS 32
#define MM (BB*PP*SS)       // 524288
#define NBLK 8192           // stat-partial stride
#define OFF_NF 49152        // 16*1024*3
#define OFF_SI 4243456      // 49152 + 16*256*1024

typedef unsigned short u16;
typedef unsigned int u32;
typedef __attribute__((ext_vector_type(8))) short short8v;
typedef __attribute__((ext_vector_type(4))) float f32x4;

__device__ __forceinline__ float b2f(u16 u) {
    union { float f; unsigned i; } x; x.i = ((unsigned)u) << 16; return x.f;
}
__device__ __forceinline__ u16 f2b(float f) {   // RTNE bf16
    union { float f; unsigned i; } x; x.f = f;
    unsigned r = x.i + 0x7fffu + ((x.i >> 16) & 1u);
    return (u16)(r >> 16);
}
__device__ __forceinline__ float2 act2(u32 u, float2 s0, float2 s1) {
    union { float f; unsigned i; } a, b;
    a.i = u << 16; b.i = u & 0xffff0000u;
    return make_float2(fmaxf(fmaf(s0.x, a.f, s0.y), 0.f),
                       fmaxf(fmaf(s1.x, b.f, s1.y), 0.f));
}
__device__ __forceinline__ u32 packbf(float flo, float fhi) {
    union { float f; unsigned i; } x0, x1; x0.f = flo; x1.f = fhi;
    return __builtin_amdgcn_perm(x1.i, x0.i, 0x07060302u);
}
__device__ __forceinline__ u32 packbf_rtne(float flo, float fhi) {
    union { float f; unsigned i; } x0, x1; x0.f = flo; x1.f = fhi;
    u32 r0 = x0.i + 0x7fffu + ((x0.i >> 16) & 1u);
    u32 r1 = x1.i + 0x7fffu + ((x1.i >> 16) & 1u);
    return __builtin_amdgcn_perm(r1, r0, 0x07060302u);
}
__device__ __forceinline__ u32 act_pack(u32 u, float2 s0, float2 s1) {
    float2 f = act2(u, s0, s1);
    return packbf(f.x, f.y);
}
__device__ __forceinline__ short8v as_s8(uint4 v) {
    union { uint4 u; short8v s; } x; x.u = v; return x.s;
}

#define MFMA16(a,b,c) __builtin_amdgcn_mfma_f32_16x16x32_bf16(a,b,c,0,0,0)

// ---------------------------------------------------------------------------
// k_init: new_xyz + sample_idxs + w0t (xyz rows, fp32) + w0b/w1b/w2b (bf16)
// ---------------------------------------------------------------------------
__global__ void k_init(const float* __restrict__ xyz, const float* __restrict__ w0,
                       const float* __restrict__ w1, const float* __restrict__ w2,
                       float* __restrict__ out, float* __restrict__ w0t,
                       u16* __restrict__ w0b, u16* __restrict__ w1b,
                       u16* __restrict__ w2b) {
    int i = blockIdx.x * 256 + threadIdx.x;
    if (i < 49152) {
        int b = i / 3072, r = i % 3072;
        out[i] = xyz[b * 12288 + r];
        return;
    }
    int j = i - 49152;
    if (j < 16384) { out[OFF_SI + j] = (float)(j & 1023); return; }
    int e = j - 16384;
    if (e < 384) { w0t[e] = w0[(e & 127) * 131 + (e >> 7)]; return; }
    int f = e - 384;
    if (f < 16384) { w0b[f] = f2b(w0[(f >> 7) * 131 + 3 + (f & 127)]); return; }
    int h = f - 16384;
    if (h < 16384) { w1b[h] = f2b(w1[h]); return; }
    int k2 = h - 16384;
    if (k2 < 32768) { w2b[k2] = f2b(w2[k2]); }
}

// ---------------------------------------------------------------------------
// k_ballquery: wave-per-center ballot scan.
// ---------------------------------------------------------------------------
__global__ __launch_bounds__(256) void k_ballquery(const float* __restrict__ xyz,
                                                   int* __restrict__ oidx,
                                                   float* __restrict__ relx,
                                                   float* __restrict__ rely,
                                                   float* __restrict__ relz) {
    __shared__ float sx[NN], sy[NN], sz[NN];
    int t = threadIdx.x, w = t >> 6, lane = t & 63;
    int b = blockIdx.x >> 8;
    int p = (blockIdx.x & 255) * 4 + w;
    const float* xb = xyz + (long)b * NN * 3;
    for (int i = t; i < NN; i += 256) {
        sx[i] = xb[3 * i]; sy[i] = xb[3 * i + 1]; sz[i] = xb[3 * i + 2];
    }
    __syncthreads();
    const float R2 = (float)(0.4 * 0.4);
    float cx = sx[p], cy = sy[p], cz = sz[p];
    int o = (b * PP + p) * SS;
    int cnt = 0, firstn = 0;
    float fdx = 0.f, fdy = 0.f, fdz = 0.f;
    for (int c = 0; c < 64 && cnt < 32; ++c) {
        int n = c * 64 + lane;
        float dx = __fsub_rn(sx[n], cx);
        float dy = __fsub_rn(sy[n], cy);
        float dz = __fsub_rn(sz[n], cz);
        float d2 = __fadd_rn(__fadd_rn(__fmul_rn(dx, dx), __fmul_rn(dy, dy)),
                             __fmul_rn(dz, dz));
        bool hit = d2 < R2;
        unsigned long long mask = __ballot(hit);
        if (mask) {
            if (cnt == 0) {
                int fl = __ffsll(mask) - 1;
                firstn = c * 64 + fl;
                fdx = __shfl(dx, fl); fdy = __shfl(dy, fl); fdz = __shfl(dz, fl);
            }
            int pos = cnt + __popcll(mask & ((1ull << lane) - 1ull));
            if (hit && pos < 32) {
                oidx[o + pos] = n;
                relx[o + pos] = dx; rely[o + pos] = dy; relz[o + pos] = dz;
            }
            cnt += __popcll(mask);
        }
    }
    if (lane < 32 && lane >= cnt) {
        oidx[o + lane] = firstn;
        relx[o + lane] = fdx; rely[o + lane] = fdy; relz[o + lane] = fdz;
    }
}

// ---------------------------------------------------------------------------
// k_f1: F1[n][co] = sum_ci feat[ci][n] * w0[co][3+ci] via MFMA (fp32 out).
// ---------------------------------------------------------------------------
__global__ __launch_bounds__(256) void k_f1(const float* __restrict__ feat,
                                            const u16* __restrict__ w0b,
                                            float* __restrict__ F1) {
    __shared__ uint4 abuf[64 * 17];
    int t = threadIdx.x;
    int w = t >> 6, lane = t & 63, q = lane >> 4, l16 = lane & 15;
    int cb = (w & 1) * 64, wm0 = (w >> 1) * 32;
    short8v bf[4][4];
#pragma unroll
    for (int ct = 0; ct < 4; ++ct)
#pragma unroll
        for (int k0 = 0; k0 < 4; ++k0)
            bf[ct][k0] = *(const short8v*)(w0b + (cb + ct * 16 + l16) * 128 + k0 * 32 + q * 8);
    int nl = t & 63, cg = t >> 6;
    const float* fcol = feat + (long)(blockIdx.x >> 6) * (128 * 4096)
                             + (long)(blockIdx.x & 63) * 64 + nl;
#pragma unroll
    for (int pp = 0; pp < 4; ++pp) {
        int oct = cg + 4 * pp;
        float v[8];
#pragma unroll
        for (int r = 0; r < 8; ++r) v[r] = fcol[(long)(oct * 8 + r) * 4096];
        uint4 ov;
        ov.x = packbf_rtne(v[0], v[1]); ov.y = packbf_rtne(v[2], v[3]);
        ov.z = packbf_rtne(v[4], v[5]); ov.w = packbf_rtne(v[6], v[7]);
        abuf[nl * 17 + ((oct + nl) & 15)] = ov;
    }
    __syncthreads();
    f32x4 acc[2][4];
#pragma unroll
    for (int mt = 0; mt < 2; ++mt)
#pragma unroll
        for (int ct = 0; ct < 4; ++ct) acc[mt][ct] = (f32x4){0.f, 0.f, 0.f, 0.f};
#pragma unroll
    for (int mt = 0; mt < 2; ++mt) {
        int row = wm0 + mt * 16 + l16;
#pragma unroll
        for (int k0 = 0; k0 < 4; ++k0) {
            uint4 vv = abuf[row * 17 + ((k0 * 4 + q + row) & 15)];
            short8v af = as_s8(vv);
#pragma unroll
            for (int ct = 0; ct < 4; ++ct)
                acc[mt][ct] = MFMA16(af, bf[ct][k0], acc[mt][ct]);
        }
    }
    long nbase = (long)blockIdx.x * 64;
#pragma unroll
    for (int mt = 0; mt < 2; ++mt)
#pragma unroll
        for (int ct = 0; ct < 4; ++ct)
#pragma unroll
            for (int r = 0; r < 4; ++r)
                F1[(nbase + wm0 + mt * 16 + q * 4 + r) * 128 + cb + ct * 16 + l16]
                    = acc[mt][ct][r];
}

// ---------------------------------------------------------------------------
// k_y0: wave reads one 512B F1 row per m (float2/lane), packed u32 stores.
// ---------------------------------------------------------------------------
__global__ __launch_bounds__(256) void k_y0(const float* __restrict__ relx,
                                            const float* __restrict__ rely,
                                            const float* __restrict__ relz,
                                            const float* __restrict__ w0t,
                                            const float* __restrict__ F1,
                                            const int* __restrict__ idx,
                                            u16* __restrict__ y0,
                                            float* __restrict__ part,
                                            float* __restrict__ partq) {
    int t = threadIdx.x, w = t >> 6, lane = t & 63;
    long m0 = (long)blockIdx.x * 64;
    int c0 = 2 * lane;
    float wx0 = w0t[c0],       wx1 = w0t[c0 + 1];
    float wy0 = w0t[128 + c0], wy1 = w0t[128 + c0 + 1];
    float wz0 = w0t[256 + c0], wz1 = w0t[256 + c0 + 1];
    float s1a = 0.f, s1b = 0.f, s2a = 0.f, s2b = 0.f;
    u32* yo = (u32*)y0;
#pragma unroll 4
    for (int i = 0; i < 16; ++i) {
        long m = m0 + w + 4 * i;
        int b = (int)(m >> 15);
        int id = idx[m];
        float rx = relx[m], ry = rely[m], rz = relz[m];
        float2 f = *(const float2*)(F1 + ((long)(b * NN + id)) * 128 + c0);
        float v0 = fmaf(wx0, rx, fmaf(wy0, ry, fmaf(wz0, rz, f.x)));
        float v1 = fmaf(wx1, rx, fmaf(wy1, ry, fmaf(wz1, rz, f.y)));
        yo[m * 64 + lane] = packbf_rtne(v0, v1);
        s1a += v0; s2a = fmaf(v0, v0, s2a);
        s1b += v1; s2b = fmaf(v1, v1, s2b);
    }
    __shared__ float r1[128][4], r2[128][4];
    r1[c0][w] = s1a; r1[c0 + 1][w] = s1b;
    r2[c0][w] = s2a; r2[c0 + 1][w] = s2b;
    __syncthreads();
    if (t < 128) {
        float a1 = r1[t][0] + r1[t][1] + r1[t][2] + r1[t][3];
        float a2 = r2[t][0] + r2[t][1] + r2[t][2] + r2[t][3];
        part [(long)t * NBLK + blockIdx.x] = a1;
        partq[(long)t * NBLK + blockIdx.x] = a2;
    }
}

// ---------------------------------------------------------------------------
// k_bnfin: reduce per-channel partials -> (scale, shift). grid = #channels.
// ---------------------------------------------------------------------------
__global__ void k_bnfin(const float* __restrict__ part, const float* __restrict__ partq,
                        const float* __restrict__ g, const float* __restrict__ beta,
                        float* __restrict__ st, int nblk) {
    int co = blockIdx.x, t = threadIdx.x;
    const float* p1 = part + (long)co * NBLK;
    const float* p2 = partq + (long)co * NBLK;
    float s1 = 0.f, s2 = 0.f;
    for (int j = t; j < nblk; j += 256) { s1 += p1[j]; s2 += p2[j]; }
    __shared__ float r1[256], r2[256];
    r1[t] = s1; r2[t] = s2; __syncthreads();
    for (int off = 128; off > 0; off >>= 1) {
        if (t < off) { r1[t] += r1[t + off]; r2[t] += r2[t + off]; }
        __syncthreads();
    }
    if (t == 0) {
        const float inv = 1.f / (float)MM;
        float mean = r1[0] * inv;
        float var = r2[0] * inv - mean * mean;
        float sc = g[co] * rsqrtf(var + 1e-5f);
        st[2 * co] = sc;
        st[2 * co + 1] = fmaf(-mean, sc, beta[co]);
    }
}

// ---------------------------------------------------------------------------
// k_conv1: y1 = W1 . act0(y0) IN-PLACE. Block = 512m x 128co, 8 chunks of 64m.
// Rotation swizzle.
// ---------------------------------------------------------------------------
__global__ __launch_bounds__(256, 3) void k_conv1(u16* __restrict__ y,
                                                  const u16* __restrict__ w1b,
                                                  const float* __restrict__ st0,
                                                  float* __restrict__ part,
                                                  float* __restrict__ partq) {
    __shared__ uint4 abuf[2][64 * 17];
    __shared__ float2 sst[128];
    __shared__ float sredA[4][64], sredB[4][64];
    int t = threadIdx.x;
    if (t < 128) sst[t] = ((const float2*)st0)[t];
    int w = t >> 6, lane = t & 63, q = lane >> 4, l16 = lane & 15;
    int wm0 = (w >> 1) * 32, cb = (w & 1) * 64;
    short8v bf[4][4];
#pragma unroll
    for (int ct = 0; ct < 4; ++ct)
#pragma unroll
        for (int k0 = 0; k0 < 4; ++k0)
            bf[ct][k0] = *(const short8v*)(w1b + (cb + ct * 16 + l16) * 128 + k0 * 32 + q * 8);
    __syncthreads();
    long m0b = (long)blockIdx.x * 512;
    float s1[4] = {0.f, 0.f, 0.f, 0.f}, s2[4] = {0.f, 0.f, 0.f, 0.f};
    int sr = t >> 4, sc16 = t & 15;
    for (int c = 0; c < 8; ++c) {
        long m0 = m0b + c * 64;
        uint4* ab = abuf[c & 1];
        const uint4* gsrc = (const uint4*)y;
#pragma unroll
        for (int p = 0; p < 4; ++p) {
            int r = p * 16 + sr;
            uint4 d = gsrc[(m0 + r) * 16 + sc16];
            uint4 o;
            o.x = act_pack(d.x, sst[sc16 * 8 + 0], sst[sc16 * 8 + 1]);
            o.y = act_pack(d.y, sst[sc16 * 8 + 2], sst[sc16 * 8 + 3]);
            o.z = act_pack(d.z, sst[sc16 * 8 + 4], sst[sc16 * 8 + 5]);
            o.w = act_pack(d.w, sst[sc16 * 8 + 6], sst[sc16 * 8 + 7]);
            ab[r * 17 + ((sc16 + r) & 15)] = o;
        }
        __syncthreads();
        f32x4 acc[2][4];
#pragma unroll
        for (int mt = 0; mt < 2; ++mt)
#pragma unroll
            for (int ct = 0; ct < 4; ++ct) acc[mt][ct] = (f32x4){0.f, 0.f, 0.f, 0.f};
#pragma unroll
        for (int mt = 0; mt < 2; ++mt) {
            int row = wm0 + mt * 16 + l16;
#pragma unroll
            for (int k0 = 0; k0 < 4; ++k0) {
                uint4 v = ab[row * 17 + ((k0 * 4 + q + row) & 15)];
                short8v af = as_s8(v);
#pragma unroll
                for (int ct = 0; ct < 4; ++ct)
                    acc[mt][ct] = MFMA16(af, bf[ct][k0], acc[mt][ct]);
            }
        }
#pragma unroll
        for (int mt = 0; mt < 2; ++mt)
#pragma unroll
            for (int ct = 0; ct < 4; ++ct)
#pragma unroll
                for (int r = 0; r < 4; ++r) {
                    float v = acc[mt][ct][r];
                    y[(m0 + wm0 + mt * 16 + q * 4 + r) * 128 + cb + ct * 16 + l16] = f2b(v);
                    s1[ct] += v; s2[ct] = fmaf(v, v, s2[ct]);
                }
    }
#pragma unroll
    for (int ct = 0; ct < 4; ++ct) {
        float a = s1[ct], b = s2[ct];
        a += __shfl_xor(a, 16); a += __shfl_xor(a, 32);
        b += __shfl_xor(b, 16); b += __shfl_xor(b, 32);
        if (lane < 16) { sredA[w][ct * 16 + l16] = a; sredB[w][ct * 16 + l16] = b; }
    }
    __syncthreads();
    if (t < 128) {
        int h = t >> 6, cl = t & 63;
        part [(long)t * NBLK + blockIdx.x] = sredA[h][cl] + sredA[h + 2][cl];
        partq[(long)t * NBLK + blockIdx.x] = sredB[h][cl] + sredB[h + 2][cl];
    }
}

// ---------------------------------------------------------------------------
// k_conv2pool: round-6 structure (B resident bf[4][4], wave = 64m x 64co,
// measured 65 us) + rotation swizzle (round 7, conflicts -82%) + fused BN2
// stat partials (round 7, gram path deleted). Raw min/max per 32-row group.
// ---------------------------------------------------------------------------
__global__ __launch_bounds__(256) void k_conv2pool(const u16* __restrict__ y1,
                                                   const u16* __restrict__ w2b,
                                                   const float* __restrict__ st1,
                                                   float* __restrict__ rawmax,
                                                   float* __restrict__ rawmin,
                                                   float* __restrict__ part,
                                                   float* __restrict__ partq) {
    __shared__ uint4 abuf[2][64 * 17];
    __shared__ float2 sst[128];
    __shared__ float sredA[4][64], sredB[4][64];
    int t = threadIdx.x;
    if (t < 128) sst[t] = ((const float2*)st1)[t];
    int w = t >> 6, lane = t & 63, q = lane >> 4, l16 = lane & 15;
    int cb = w * 64;
    short8v bf[4][4];
#pragma unroll
    for (int ct = 0; ct < 4; ++ct)
#pragma unroll
        for (int k0 = 0; k0 < 4; ++k0)
            bf[ct][k0] = *(const short8v*)(w2b + (cb + ct * 16 + l16) * 128 + k0 * 32 + q * 8);
    __syncthreads();
    long m0b = (long)blockIdx.x * 512;
    int sr = t >> 4, sc16 = t & 15;
    float s1[4] = {0.f, 0.f, 0.f, 0.f}, s2[4] = {0.f, 0.f, 0.f, 0.f};
    for (int c = 0; c < 8; ++c) {
        long m0 = m0b + c * 64;
        uint4* ab = abuf[c & 1];
        const uint4* gsrc = (const uint4*)y1;
#pragma unroll
        for (int p = 0; p < 4; ++p) {
            int r = p * 16 + sr;
            uint4 d = gsrc[(m0 + r) * 16 + sc16];
            uint4 o;
            o.x = act_pack(d.x, sst[sc16 * 8 + 0], sst[sc16 * 8 + 1]);
            o.y = act_pack(d.y, sst[sc16 * 8 + 2], sst[sc16 * 8 + 3]);
            o.z = act_pack(d.z, sst[sc16 * 8 + 4], sst[sc16 * 8 + 5]);
            o.w = act_pack(d.w, sst[sc16 * 8 + 6], sst[sc16 * 8 + 7]);
            ab[r * 17 + ((sc16 + r) & 15)] = o;
        }
        __syncthreads();
        f32x4 acc[4][4];
#pragma unroll
        for (int mt = 0; mt < 4; ++mt)
#pragma unroll
            for (int ct = 0; ct < 4; ++ct) acc[mt][ct] = (f32x4){0.f, 0.f, 0.f, 0.f};
#pragma unroll
        for (int mt = 0; mt < 4; ++mt) {
            int row = mt * 16 + l16;
#pragma unroll
            for (int k0 = 0; k0 < 4; ++k0) {
                uint4 v = ab[row * 17 + ((k0 * 4 + q + row) & 15)];
                short8v af = as_s8(v);
#pragma unroll
                for (int ct = 0; ct < 4; ++ct)
                    acc[mt][ct] = MFMA16(af, bf[ct][k0], acc[mt][ct]);
            }
        }
        // pooling per 32-row group (mt pairs) + stats over all rows
#pragma unroll
        for (int ct = 0; ct < 4; ++ct) {
#pragma unroll
            for (int g = 0; g < 2; ++g) {
                f32x4 a0 = acc[2 * g][ct], a1 = acc[2 * g + 1][ct];
                s1[ct] += a0[0] + a0[1] + a0[2] + a0[3] + a1[0] + a1[1] + a1[2] + a1[3];
                s2[ct] = fmaf(a0[0], a0[0], s2[ct]); s2[ct] = fmaf(a0[1], a0[1], s2[ct]);
                s2[ct] = fmaf(a0[2], a0[2], s2[ct]); s2[ct] = fmaf(a0[3], a0[3], s2[ct]);
                s2[ct] = fmaf(a1[0], a1[0], s2[ct]); s2[ct] = fmaf(a1[1], a1[1], s2[ct]);
                s2[ct] = fmaf(a1[2], a1[2], s2[ct]); s2[ct] = fmaf(a1[3], a1[3], s2[ct]);
                float mx = fmaxf(fmaxf(fmaxf(a0[0], a0[1]), fmaxf(a0[2], a0[3])),
                                 fmaxf(fmaxf(a1[0], a1[1]), fmaxf(a1[2], a1[3])));
                float mn = fminf(fminf(fminf(a0[0], a0[1]), fminf(a0[2], a0[3])),
                                 fminf(fminf(a1[0], a1[1]), fminf(a1[2], a1[3])));
                mx = fmaxf(mx, __shfl_xor(mx, 16)); mx = fmaxf(mx, __shfl_xor(mx, 32));
                mn = fminf(mn, __shfl_xor(mn, 16)); mn = fminf(mn, __shfl_xor(mn, 32));
                if (lane < 16) {
                    long bp = (long)blockIdx.x * 16 + c * 2 + g;
                    rawmax[bp * 256 + cb + ct * 16 + l16] = mx;
                    rawmin[bp * 256 + cb + ct * 16 + l16] = mn;
                }
            }
        }
    }
    // stat reduction: shfl over q, then one thread per channel writes partials
#pragma unroll
    for (int ct = 0; ct < 4; ++ct) {
        float a = s1[ct], b = s2[ct];
        a += __shfl_xor(a, 16); a += __shfl_xor(a, 32);
        b += __shfl_xor(b, 16); b += __shfl_xor(b, 32);
        if (lane < 16) { sredA[w][ct * 16 + l16] = a; sredB[w][ct * 16 + l16] = b; }
    }
    __syncthreads();
    {
        // co = t: wave t>>6 owns cols (t>>6)*64 + (t&63)
        part [(long)t * NBLK + blockIdx.x] = sredA[t >> 6][t & 63];
        partq[(long)t * NBLK + blockIdx.x] = sredB[t >> 6][t & 63];
    }
}

// ---------------------------------------------------------------------------
// k_final: z = relu(sc>0 ? sc*max+sh : sc*min+sh); transpose to out[b][co][p].
// ---------------------------------------------------------------------------
__global__ void k_final(const float* __restrict__ rawmax, const float* __restrict__ rawmin,
                        const float* __restrict__ st2, float* __restrict__ out) {
    __shared__ float tile[32][33];
    int b = blockIdx.x >> 8;
    int p0 = ((blockIdx.x >> 3) & 31) * 32;
    int c0 = (blockIdx.x & 7) * 32;
    int j = threadIdx.x & 31, i0 = threadIdx.x >> 5;
    float sc = st2[2 * (c0 + j)], sh = st2[2 * (c0 + j) + 1];
#pragma unroll
    for (int rr = 0; rr < 4; ++rr) {
        int i = i0 + rr * 8;
        long idx = ((long)(b * 1024 + p0 + i)) * 256 + c0 + j;
        float v = sc > 0.f ? fmaf(sc, rawmax[idx], sh) : fmaf(sc, rawmin[idx], sh);
        tile[i][j] = fmaxf(v, 0.f);
    }
    __syncthreads();
#pragma unroll
    for (int rr = 0; rr < 4; ++rr) {
        int i = i0 + rr * 8;
        out[OFF_NF + (long)b * 262144 + (c0 + i) * 1024 + p0 + j] = tile[j][i];
    }
}

// ---------------------------------------------------------------------------
extern "C" void kernel_launch(void* const* d_in, const int* in_sizes, int n_in,
                              void* d_out, int out_size, void* d_ws, size_t ws_size,
                              hipStream_t stream) {
    (void)in_sizes; (void)n_in; (void)out_size; (void)ws_size;
    const float* xyz  = (const float*)d_in[0];
    const float* feat = (const float*)d_in[1];
    const float* w0   = (const float*)d_in[3];
    const float* g0   = (const float*)d_in[5];
    const float* be0  = (const float*)d_in[6];
    const float* w1   = (const float*)d_in[7];
    const float* g1   = (const float*)d_in[9];
    const float* be1  = (const float*)d_in[10];
    const float* w2   = (const float*)d_in[11];
    const float* g2   = (const float*)d_in[13];
    const float* be2  = (const float*)d_in[14];
    float* out = (float*)d_out;

    char* ws = (char*)d_ws;
    size_t off = 0;
    auto alloc = [&](size_t bytes) -> void* {
        void* p = ws + off;
        off = (off + bytes + 4095) & ~(size_t)4095;
        return p;
    };
    int*   idx    = (int*)  alloc((size_t)MM * 4);            // 2 MB
    float* relx   = (float*)alloc((size_t)MM * 4);            // 2 MB
    float* rely   = (float*)alloc((size_t)MM * 4);            // 2 MB
    float* relz   = (float*)alloc((size_t)MM * 4);            // 2 MB
    float* w0t    = (float*)alloc(3 * 128 * 4);
    u16*   w0b    = (u16*)  alloc(128 * 128 * 2);
    u16*   w1b    = (u16*)  alloc(128 * 128 * 2);
    u16*   w2b    = (u16*)  alloc(256 * 128 * 2);
    float* st0    = (float*)alloc(128 * 2 * 4);
    float* st1    = (float*)alloc(128 * 2 * 4);
    float* st2    = (float*)alloc(256 * 2 * 4);
    float* part   = (float*)alloc((size_t)256 * NBLK * 4);    // 8 MB
    float* partq  = (float*)alloc((size_t)256 * NBLK * 4);    // 8 MB
    float* F1     = (float*)alloc((size_t)BB * NN * 128 * 4); // 33.5 MB
    float* rawmax = (float*)alloc((size_t)BB * PP * 256 * 4); // 16 MB
    float* rawmin = (float*)alloc((size_t)BB * PP * 256 * 4); // 16 MB
    u16*   bufA   = (u16*)  alloc((size_t)MM * 128 * 2);      // 134 MB (y0 -> y1 in place)
    // total ~225 MB

    k_init<<<514, 256, 0, stream>>>(xyz, w0, w1, w2, out, w0t, w0b, w1b, w2b);
    k_ballquery<<<4096, 256, 0, stream>>>(xyz, idx, relx, rely, relz);
    k_f1<<<1024, 256, 0, stream>>>(feat, w0b, F1);
    k_y0<<<NBLK, 256, 0, stream>>>(relx, rely, relz, w0t, F1, idx, bufA, part, partq);
    k_bnfin<<<128, 256, 0, stream>>>(part, partq, g0, be0, st0, NBLK);
    k_conv1<<<1024, 256, 0, stream>>>(bufA, w1b, st0, part, partq);
    k_bnfin<<<128, 256, 0, stream>>>(part, partq, g1, be1, st1, 1024);
    k_conv2pool<<<1024, 256, 0, stream>>>(bufA, w2b, st1, rawmax, rawmin, part, partq);
    k_bnfin<<<256, 256, 0, stream>>>(part, partq, g2, be2, st2, 1024);
    k_final<<<4096, 256, 0, stream>>>(rawmax, rawmin, st2, out);
}